// Round 8
// baseline (294.543 us; speedup 1.0000x reference)
//
#include <hip/hip_runtime.h>
#include <hip/hip_bf16.h>

#define HC 256        // HEADS*OUT_CH
#define NEG_SLOPE 0.2f
#define BM 128
#define BK 64
#define LDK 72        // padded LDS k-stride (bf16 elems): 144B rows, 16B-aligned

typedef short short8_t __attribute__((ext_vector_type(8)));
typedef float float4_t __attribute__((ext_vector_type(4)));

__device__ __forceinline__ unsigned short f2bf(float f) {
  unsigned u = __float_as_uint(f);
  return (unsigned short)((u + 0x7fffu + ((u >> 16) & 1u)) >> 16);  // RNE
}
__device__ __forceinline__ float bf2f(unsigned short b) {
  return __uint_as_float(((unsigned)b) << 16);
}

// ---------------------------------------------------------------------------
// K0: Wt[n][k] = bf16(W[k][n]).  256x256, tiny.
// ---------------------------------------------------------------------------
__global__ void wt_kernel(const float* __restrict__ W, unsigned short* __restrict__ Wt)
{
  const int k = blockIdx.x;
  const int n = threadIdx.x;
  Wt[n * 256 + k] = f2bf(W[k * 256 + n]);
}

// ---------------------------------------------------------------------------
// K1: fused deg_count + MFMA GEMM in one dispatch.
// Blocks [0, degBlocks): degree histogram. Blocks [degBlocks, ...): 128x256
// gemm tile, BK=64, bf16 MFMA, fp32 acc, fused a_src/a_dst epilogue.
// ---------------------------------------------------------------------------
__global__ __launch_bounds__(256) void gemm_deg(
    const float* __restrict__ x, const unsigned short* __restrict__ Wt,
    const float* __restrict__ att_src, const float* __restrict__ att_dst,
    unsigned short* __restrict__ h, float* __restrict__ a_src,
    float* __restrict__ a_dst, const int* __restrict__ ei,
    int* __restrict__ deg, int E, int nnodes, int degBlocks)
{
  __shared__ unsigned short As[BM * LDK];    // 18432 B
  __shared__ unsigned short Bs[256 * LDK];   // 36864 B  (total 55296)
  const int t = threadIdx.x;

  if (blockIdx.x < degBlocks) {
    const int base = (blockIdx.x * 256 + t) * 4;
    if (base + 3 < E) {
      const int4 d4 = *(const int4*)&ei[E + base];
      atomicAdd(&deg[d4.x], 1);
      atomicAdd(&deg[d4.y], 1);
      atomicAdd(&deg[d4.z], 1);
      atomicAdd(&deg[d4.w], 1);
    } else {
      for (int e = base; e < E; ++e) atomicAdd(&deg[ei[E + e]], 1);
    }
    return;
  }

  const int wv   = t >> 6;
  const int lane = t & 63;
  const int r0   = (blockIdx.x - degBlocks) * BM;

  float4_t acc[8][4] = {};   // [mt][nt]

  for (int k0 = 0; k0 < 256; k0 += BK) {
    __syncthreads();
    // stage A: thread t -> row t>>1, k-chunk (t&1)*32 (32 floats -> 32 bf16)
    {
      const int row = t >> 1, kc = (t & 1) * 32;
      const int gr = r0 + row;
      float4 xv[8];
      if (gr < nnodes) {
        const float4* p = (const float4*)(x + (size_t)gr * 256 + k0 + kc);
        #pragma unroll
        for (int i = 0; i < 8; ++i) xv[i] = p[i];
      } else {
        #pragma unroll
        for (int i = 0; i < 8; ++i) xv[i] = make_float4(0.f, 0.f, 0.f, 0.f);
      }
      const float* f = (const float*)xv;
      unsigned pk[16];
      #pragma unroll
      for (int i = 0; i < 16; ++i) {
        __hip_bfloat162 b2 = __float22bfloat162_rn(make_float2(f[2 * i], f[2 * i + 1]));
        pk[i] = *(unsigned*)&b2;
      }
      uint4* d = (uint4*)&As[row * LDK + kc];
      #pragma unroll
      for (int i = 0; i < 4; ++i)
        d[i] = make_uint4(pk[4 * i], pk[4 * i + 1], pk[4 * i + 2], pk[4 * i + 3]);
    }
    // stage B: Wt rows (already bf16): 256 rows x 64 k
    #pragma unroll
    for (int it = 0; it < 4; ++it) {
      const int n = it * 64 + (t >> 2);
      const int kc = (t & 3) * 16;
      const uint4* g = (const uint4*)(Wt + (size_t)n * 256 + k0 + kc);
      uint4 v0 = g[0], v1 = g[1];
      uint4* d = (uint4*)&Bs[n * LDK + kc];
      d[0] = v0; d[1] = v1;
    }
    __syncthreads();

    #pragma unroll
    for (int ks = 0; ks < 2; ++ks) {
      const int ko = ks * 32 + (lane >> 4) * 8;
      short8_t af[8], bfr[4];
      #pragma unroll
      for (int nt = 0; nt < 4; ++nt)
        bfr[nt] = *(const short8_t*)&Bs[(64 * wv + 16 * nt + (lane & 15)) * LDK + ko];
      #pragma unroll
      for (int mt = 0; mt < 8; ++mt)
        af[mt] = *(const short8_t*)&As[(16 * mt + (lane & 15)) * LDK + ko];
      #pragma unroll
      for (int mt = 0; mt < 8; ++mt)
        #pragma unroll
        for (int nt = 0; nt < 4; ++nt)
          acc[mt][nt] = __builtin_amdgcn_mfma_f32_16x16x32_bf16(
              af[mt], bfr[nt], acc[mt][nt], 0, 0, 0);
    }
  }

  const int q = lane >> 4, l15 = lane & 15;
  float atts[4], attd[4];
  #pragma unroll
  for (int nt = 0; nt < 4; ++nt) {
    atts[nt] = att_src[wv * 64 + 16 * nt + l15];
    attd[nt] = att_dst[wv * 64 + 16 * nt + l15];
  }

  #pragma unroll
  for (int mt = 0; mt < 8; ++mt) {
    #pragma unroll
    for (int reg = 0; reg < 4; ++reg) {
      const int row = r0 + 16 * mt + 4 * q + reg;
      const bool ok = row < nnodes;
      float ps = 0.f, pd = 0.f;
      #pragma unroll
      for (int nt = 0; nt < 4; ++nt) {
        const float v = acc[mt][nt][reg];
        if (ok) h[(size_t)row * 256 + 64 * wv + 16 * nt + l15] = f2bf(v);
        ps += v * atts[nt];
        pd += v * attd[nt];
      }
      #pragma unroll
      for (int off = 8; off; off >>= 1) {
        ps += __shfl_down(ps, off, 16);
        pd += __shfl_down(pd, off, 16);
      }
      if (ok && l15 == 0) {
        a_src[row * 4 + wv] = ps;
        a_dst[row * 4 + wv] = pd;
      }
    }
  }
}

// ---------------------------------------------------------------------------
// 3-phase hierarchical exclusive scan (unchanged)
// ---------------------------------------------------------------------------
__global__ __launch_bounds__(256) void scan_p1(const int* __restrict__ deg,
                                               int* __restrict__ bsum, int n)
{
  __shared__ int ws[4];
  const int t = threadIdx.x, lane = t & 63, wv = t >> 6;
  const int base = blockIdx.x * 1024 + t * 4;
  int4 v = make_int4(0, 0, 0, 0);
  if (base + 3 < n) v = *(const int4*)&deg[base];
  else {
    if (base + 0 < n) v.x = deg[base + 0];
    if (base + 1 < n) v.y = deg[base + 1];
    if (base + 2 < n) v.z = deg[base + 2];
  }
  int s = (v.x + v.y) + (v.z + v.w);
  #pragma unroll
  for (int off = 32; off; off >>= 1) s += __shfl_down(s, off, 64);
  if (lane == 0) ws[wv] = s;
  __syncthreads();
  if (t == 0) bsum[blockIdx.x] = (ws[0] + ws[1]) + (ws[2] + ws[3]);
}

__global__ __launch_bounds__(1024) void scan_p2(const int* __restrict__ bsum,
                                                int* __restrict__ boff,
                                                int* __restrict__ rowptr,
                                                int nb, int n)
{
  __shared__ int wsum[16], woff[16];
  const int t = threadIdx.x, lane = t & 63, wv = t >> 6;
  int v = (t < nb) ? bsum[t] : 0;
  int sc = v;
  #pragma unroll
  for (int off = 1; off < 64; off <<= 1) {
    int u = __shfl_up(sc, off, 64);
    if (lane >= off) sc += u;
  }
  if (lane == 63) wsum[wv] = sc;
  __syncthreads();
  if (t == 0) {
    int run = 0;
    #pragma unroll
    for (int i = 0; i < 16; ++i) { int x = wsum[i]; woff[i] = run; run += x; }
    rowptr[n] = run;
  }
  __syncthreads();
  if (t < nb) boff[t] = woff[wv] + sc - v;
}

__global__ __launch_bounds__(256) void scan_p3(const int* __restrict__ deg,
                                               const int* __restrict__ boff,
                                               int* __restrict__ rowptr,
                                               int* __restrict__ cursor, int n)
{
  __shared__ int wsum[4], woff[4];
  const int t = threadIdx.x, lane = t & 63, wv = t >> 6;
  const int base = blockIdx.x * 1024 + t * 4;
  int4 v = make_int4(0, 0, 0, 0);
  if (base + 3 < n) v = *(const int4*)&deg[base];
  else {
    if (base + 0 < n) v.x = deg[base + 0];
    if (base + 1 < n) v.y = deg[base + 1];
    if (base + 2 < n) v.z = deg[base + 2];
  }
  const int s = (v.x + v.y) + (v.z + v.w);
  int sc = s;
  #pragma unroll
  for (int off = 1; off < 64; off <<= 1) {
    int u = __shfl_up(sc, off, 64);
    if (lane >= off) sc += u;
  }
  if (lane == 63) wsum[wv] = sc;
  __syncthreads();
  if (t == 0) {
    int run = 0;
    #pragma unroll
    for (int i = 0; i < 4; ++i) { int x = wsum[i]; woff[i] = run; run += x; }
  }
  __syncthreads();
  int excl = boff[blockIdx.x] + woff[wv] + (sc - s);
  int4 r;
  r.x = excl;
  r.y = r.x + v.x;
  r.z = r.y + v.y;
  r.w = r.z + v.z;
  if (base + 3 < n) {
    *(int4*)&rowptr[base] = r;
    *(int4*)&cursor[base] = r;
  } else {
    if (base + 0 < n) { rowptr[base + 0] = r.x; cursor[base + 0] = r.x; }
    if (base + 1 < n) { rowptr[base + 1] = r.y; cursor[base + 1] = r.y; }
    if (base + 2 < n) { rowptr[base + 2] = r.z; cursor[base + 2] = r.z; }
  }
}

// ---------------------------------------------------------------------------
// fill_csr, XCD-grouped (group g=blockIdx&7 owns dst range g), int4 edge
// loads. Writes csr_src + per-edge per-head weights wexp.
// ---------------------------------------------------------------------------
__device__ __forceinline__ void fill_one(
    int s, int d, int dlo, int dhi, const float* __restrict__ a_src,
    const float* __restrict__ a_dst, int* __restrict__ cursor,
    int* __restrict__ csr_src, float4* __restrict__ wexp)
{
  if (d < dlo || d >= dhi) return;
  const int pos = atomicAdd(&cursor[d], 1);
  csr_src[pos] = s;
  const float4 as = ((const float4*)a_src)[s];
  const float4 ad = ((const float4*)a_dst)[d];
  float4 al;
  al.x = as.x + ad.x; al.y = as.y + ad.y;
  al.z = as.z + ad.z; al.w = as.w + ad.w;
  al.x = al.x > 0.f ? al.x : NEG_SLOPE * al.x;
  al.y = al.y > 0.f ? al.y : NEG_SLOPE * al.y;
  al.z = al.z > 0.f ? al.z : NEG_SLOPE * al.z;
  al.w = al.w > 0.f ? al.w : NEG_SLOPE * al.w;
  al.x = expf(al.x); al.y = expf(al.y); al.z = expf(al.z); al.w = expf(al.w);
  wexp[pos] = al;
}

__global__ __launch_bounds__(256) void fill_csr(
    const int* __restrict__ ei, const float* __restrict__ a_src,
    const float* __restrict__ a_dst, int* __restrict__ cursor,
    int* __restrict__ csr_src, float4* __restrict__ wexp, int E, int nnodes)
{
  const int g    = blockIdx.x & 7;
  const int bg   = blockIdx.x >> 3;
  const int nbg  = gridDim.x >> 3;
  const int gsz  = (nnodes + 7) >> 3;
  const int dlo  = g * gsz;
  const int dhi  = min(dlo + gsz, nnodes);
  const int E4   = E >> 2;

  for (int c = bg * 256 + threadIdx.x; c < E4; c += nbg * 256) {
    const int4 d4 = *(const int4*)&ei[E + 4 * c];
    const int4 s4 = *(const int4*)&ei[4 * c];
    fill_one(s4.x, d4.x, dlo, dhi, a_src, a_dst, cursor, csr_src, wexp);
    fill_one(s4.y, d4.y, dlo, dhi, a_src, a_dst, cursor, csr_src, wexp);
    fill_one(s4.z, d4.z, dlo, dhi, a_src, a_dst, cursor, csr_src, wexp);
    fill_one(s4.w, d4.w, dlo, dhi, a_src, a_dst, cursor, csr_src, wexp);
  }
  for (int e = E4 * 4 + bg * 256 + threadIdx.x; e < E; e += nbg * 256)
    fill_one(ei[e], ei[E + e], dlo, dhi, a_src, a_dst, cursor, csr_src, wexp);
}

// ---------------------------------------------------------------------------
// K3: gather with BIJECTIVE XCD swizzle: grid padded to a multiple of 8, so
// per8 = gridDim/8 is exact and vb = (b&7)*per8 + (b>>3) is a permutation.
// (Round-7 bug: unpadded grid made the map non-surjective — 3 virtual blocks
// = 12 dst nodes never processed.)
// ---------------------------------------------------------------------------
__device__ __forceinline__ float4 ld_h(const unsigned short* __restrict__ h,
                                       int row, int cb)
{
  const ushort4 u = *(const ushort4*)&h[(size_t)row * 256 + cb];
  return make_float4(bf2f(u.x), bf2f(u.y), bf2f(u.z), bf2f(u.w));
}

__global__ __launch_bounds__(256) void gather_kernel(
    const int* __restrict__ rowptr, const int* __restrict__ csr_src,
    const float* __restrict__ wexp, const unsigned short* __restrict__ h,
    const float* __restrict__ a_src, const float* __restrict__ a_dst,
    const float* __restrict__ bias, float* __restrict__ out, int n)
{
  const int per8 = gridDim.x >> 3;   // gridDim.x is a multiple of 8
  const int vb   = (blockIdx.x & 7) * per8 + (blockIdx.x >> 3);
  const int wave = threadIdx.x >> 6;
  const int lane = threadIdx.x & 63;
  const int d = vb * 4 + wave;
  if (d >= n) return;

  const int head = lane >> 4;
  const int cb   = lane * 4;

  // self-loop (weight computed inline; not in csr)
  float alpha = a_src[d * 4 + head] + a_dst[d * 4 + head];
  alpha = alpha > 0.f ? alpha : NEG_SLOPE * alpha;
  float w = expf(alpha);
  float dsum = w;
  float4 hv = ld_h(h, d, cb);
  float4 acc = make_float4(w * hv.x, w * hv.y, w * hv.z, w * hv.w);

  int j = rowptr[d];
  const int end = rowptr[d + 1];

  for (; j + 7 < end; j += 8) {
    const int4 sa = *(const int4*)&csr_src[j];
    const int4 sb = *(const int4*)&csr_src[j + 4];
    float wj[8];
    #pragma unroll
    for (int k = 0; k < 8; ++k) wj[k] = wexp[(j + k) * 4 + head];
    const float4 h0 = ld_h(h, sa.x, cb);
    const float4 h1 = ld_h(h, sa.y, cb);
    const float4 h2 = ld_h(h, sa.z, cb);
    const float4 h3 = ld_h(h, sa.w, cb);
    const float4 h4 = ld_h(h, sb.x, cb);
    const float4 h5 = ld_h(h, sb.y, cb);
    const float4 h6 = ld_h(h, sb.z, cb);
    const float4 h7 = ld_h(h, sb.w, cb);
    dsum += ((wj[0] + wj[1]) + (wj[2] + wj[3])) + ((wj[4] + wj[5]) + (wj[6] + wj[7]));
    acc.x += wj[0] * h0.x + wj[1] * h1.x + wj[2] * h2.x + wj[3] * h3.x
           + wj[4] * h4.x + wj[5] * h5.x + wj[6] * h6.x + wj[7] * h7.x;
    acc.y += wj[0] * h0.y + wj[1] * h1.y + wj[2] * h2.y + wj[3] * h3.y
           + wj[4] * h4.y + wj[5] * h5.y + wj[6] * h6.y + wj[7] * h7.y;
    acc.z += wj[0] * h0.z + wj[1] * h1.z + wj[2] * h2.z + wj[3] * h3.z
           + wj[4] * h4.z + wj[5] * h5.z + wj[6] * h6.z + wj[7] * h7.z;
    acc.w += wj[0] * h0.w + wj[1] * h1.w + wj[2] * h2.w + wj[3] * h3.w
           + wj[4] * h4.w + wj[5] * h5.w + wj[6] * h6.w + wj[7] * h7.w;
  }
  for (; j < end; ++j) {
    const int s0 = csr_src[j];
    const float w0 = wexp[j * 4 + head];
    const float4 h0 = ld_h(h, s0, cb);
    dsum += w0;
    acc.x += w0 * h0.x; acc.y += w0 * h0.y;
    acc.z += w0 * h0.z; acc.w += w0 * h0.w;
  }

  const float inv = 1.f / (dsum + 1e-16f);
  const float4 b4 = ((const float4*)bias)[lane];
  float4 o;
  o.x = acc.x * inv + b4.x; o.x = o.x > 0.f ? o.x : 0.f;
  o.y = acc.y * inv + b4.y; o.y = o.y > 0.f ? o.y : 0.f;
  o.z = acc.z * inv + b4.z; o.z = o.z > 0.f ? o.z : 0.f;
  o.w = acc.w * inv + b4.w; o.w = o.w > 0.f ? o.w : 0.f;
  *(float4*)&out[(size_t)d * 256 + cb] = o;
}

extern "C" void kernel_launch(void* const* d_in, const int* in_sizes, int n_in,
                              void* d_out, int out_size, void* d_ws, size_t ws_size,
                              hipStream_t stream)
{
  const float* x       = (const float*)d_in[0];
  const int*   ei      = (const int*)d_in[1];
  const float* W       = (const float*)d_in[2];
  const float* att_src = (const float*)d_in[3];
  const float* att_dst = (const float*)d_in[4];
  const float* bias    = (const float*)d_in[5];

  const int nnodes = in_sizes[0] / HC;   // 50000
  const int E      = in_sizes[1] / 2;    // 800000
  const int nb     = (nnodes + 1023) / 1024;   // scan blocks (49)
  const int degBlocks  = (E + 1023) / 1024;    // 782
  const int gemmBlocks = (nnodes + BM - 1) / BM;  // 391
  const int gatherBlocks = (((nnodes + 3) / 4) + 7) & ~7;  // multiple of 8

  float* out = (float*)d_out;
  char* ws = (char*)d_ws;
  // Workspace (~44 MB), all segments 16B-aligned:
  unsigned short* h  = (unsigned short*)ws;                          // nnodes*256 bf16
  float* a_src = (float*)(ws + (size_t)nnodes * HC * 2);             // nnodes*4 f32
  float* a_dst = a_src + (size_t)nnodes * 4;
  unsigned short* Wt = (unsigned short*)(a_dst + (size_t)nnodes * 4); // 256*256 bf16
  int* deg    = (int*)((char*)Wt + 256 * 256 * 2);                   // nnodes
  int* rowptr = deg + nnodes;                                        // nnodes+1 (pad x4)
  int* cursor = rowptr + ((nnodes + 1 + 3) & ~3);                    // nnodes
  int* bsum   = cursor + nnodes;                                     // nb
  int* boff   = bsum + ((nb + 3) & ~3);                              // nb
  float4* wexp = (float4*)(boff + ((nb + 3) & ~3));                  // E float4 (12.8 MB)
  int* csr    = (int*)(wexp + E);                                    // E

  hipMemsetAsync(deg, 0, (size_t)nnodes * sizeof(int), stream);

  wt_kernel<<<256, 256, 0, stream>>>(W, Wt);

  gemm_deg<<<degBlocks + gemmBlocks, 256, 0, stream>>>(
      x, Wt, att_src, att_dst, h, a_src, a_dst, ei, deg, E, nnodes, degBlocks);

  scan_p1<<<nb, 256, 0, stream>>>(deg, bsum, nnodes);
  scan_p2<<<1, 1024, 0, stream>>>(bsum, boff, rowptr, nb, nnodes);
  scan_p3<<<nb, 256, 0, stream>>>(deg, boff, rowptr, cursor, nnodes);

  fill_csr<<<1024, 256, 0, stream>>>(ei, a_src, a_dst, cursor, csr,
                                     (float4*)wexp, E, nnodes);

  gather_kernel<<<gatherBlocks, 256, 0, stream>>>(
      rowptr, csr, (const float*)wexp, h, a_src, a_dst, bias, out, nnodes);
}

// Round 9
// 282.703 us; speedup vs baseline: 1.0419x; 1.0419x over previous
//
#include <hip/hip_runtime.h>
#include <hip/hip_bf16.h>

#define HC 256        // HEADS*OUT_CH
#define NEG_SLOPE 0.2f
#define LDA 264       // padded LDS A-row stride in bf16 elems (528 B, 16B-aligned)

typedef short short8_t __attribute__((ext_vector_type(8)));
typedef float float4_t __attribute__((ext_vector_type(4)));

__device__ __forceinline__ unsigned short f2bf(float f) {
  unsigned u = __float_as_uint(f);
  return (unsigned short)((u + 0x7fffu + ((u >> 16) & 1u)) >> 16);  // RNE
}
__device__ __forceinline__ float bf2f(unsigned short b) {
  return __uint_as_float(((unsigned)b) << 16);
}

// ---------------------------------------------------------------------------
// K0: fused Wt-transpose + degree histogram (independent inputs/outputs).
// Blocks [0,256): Wt[n][k] = bf16(W[k][n]). Blocks [256,...): deg atomics.
// ---------------------------------------------------------------------------
__global__ void wt_deg(const float* __restrict__ W, unsigned short* __restrict__ Wt,
                       const int* __restrict__ ei, int* __restrict__ deg, int E)
{
  if (blockIdx.x < 256) {
    const int k = blockIdx.x;
    const int n = threadIdx.x;
    Wt[n * 256 + k] = f2bf(W[k * 256 + n]);
    return;
  }
  const int base = ((blockIdx.x - 256) * 256 + threadIdx.x) * 4;
  if (base + 3 < E) {
    const int4 d4 = *(const int4*)&ei[E + base];
    atomicAdd(&deg[d4.x], 1);
    atomicAdd(&deg[d4.y], 1);
    atomicAdd(&deg[d4.z], 1);
    atomicAdd(&deg[d4.w], 1);
  } else {
    for (int e = base; e < E; ++e) atomicAdd(&deg[ei[E + e]], 1);
  }
}

// ---------------------------------------------------------------------------
// K1: h = x @ W via bf16 MFMA, fp32 acc, fused a_src/a_dst epilogue.
// Round-9 structure: A tile (64 rows x full K=256) staged in LDS ONCE
// (single __syncthreads), B fragments loaded directly from global Wt
// (128 KB, L2-resident) inside the unrolled 8-step K-loop — no Bs LDS,
// no K-loop barriers (round-8's BM=128 2-blocks/CU barrier-drain regression
// reverted). LDS 33.8 KB -> 4 blocks/CU by LDS.
// MFMA 16x16x32: A[m=lane&15][k=quad*8+j], B[n=lane&15][k], C/D col=lane&15,
// row=quad*4+reg (verified layouts, rounds 4-8 pass).
// ---------------------------------------------------------------------------
__global__ __launch_bounds__(256) void gemm_mfma(
    const float* __restrict__ x, const unsigned short* __restrict__ Wt,
    const float* __restrict__ att_src, const float* __restrict__ att_dst,
    unsigned short* __restrict__ h, float* __restrict__ a_src,
    float* __restrict__ a_dst, int nnodes)
{
  __shared__ unsigned short As[64 * LDA];   // 33792 B
  const int t    = threadIdx.x;
  const int wv   = t >> 6;
  const int lane = t & 63;
  const int r0   = blockIdx.x * 64;

  // stage A: thread t -> row t>>2, k-chunk (t&3)*64 (64 floats -> 64 bf16)
  {
    const int row = t >> 2;
    const int kc  = (t & 3) * 64;
    const int gr  = r0 + row;
    unsigned pk[32];
    if (gr < nnodes) {
      const float4* p = (const float4*)(x + (size_t)gr * 256 + kc);
      #pragma unroll
      for (int i = 0; i < 16; ++i) {
        const float4 v = p[i];
        __hip_bfloat162 b0 = __float22bfloat162_rn(make_float2(v.x, v.y));
        __hip_bfloat162 b1 = __float22bfloat162_rn(make_float2(v.z, v.w));
        pk[2 * i]     = *(unsigned*)&b0;
        pk[2 * i + 1] = *(unsigned*)&b1;
      }
    } else {
      #pragma unroll
      for (int i = 0; i < 32; ++i) pk[i] = 0;
    }
    uint4* d = (uint4*)&As[row * LDA + kc];
    #pragma unroll
    for (int i = 0; i < 8; ++i)
      d[i] = make_uint4(pk[4 * i], pk[4 * i + 1], pk[4 * i + 2], pk[4 * i + 3]);
  }
  __syncthreads();

  const int q = lane >> 4, l15 = lane & 15;
  float4_t acc[4][4] = {};   // [mt][nt]

  #pragma unroll
  for (int ks = 0; ks < 8; ++ks) {
    const int ko = ks * 32 + q * 8;
    short8_t bfr[4], af[4];
    #pragma unroll
    for (int nt = 0; nt < 4; ++nt)
      bfr[nt] = *(const short8_t*)&Wt[(size_t)(64 * wv + 16 * nt + l15) * 256 + ko];
    #pragma unroll
    for (int mt = 0; mt < 4; ++mt)
      af[mt] = *(const short8_t*)&As[(16 * mt + l15) * LDA + ko];
    #pragma unroll
    for (int mt = 0; mt < 4; ++mt)
      #pragma unroll
      for (int nt = 0; nt < 4; ++nt)
        acc[mt][nt] = __builtin_amdgcn_mfma_f32_16x16x32_bf16(
            af[mt], bfr[nt], acc[mt][nt], 0, 0, 0);
  }

  // epilogue: write h (bf16), reduce a_src/a_dst per (row, head=wv)
  float atts[4], attd[4];
  #pragma unroll
  for (int nt = 0; nt < 4; ++nt) {
    atts[nt] = att_src[wv * 64 + 16 * nt + l15];
    attd[nt] = att_dst[wv * 64 + 16 * nt + l15];
  }

  #pragma unroll
  for (int mt = 0; mt < 4; ++mt) {
    #pragma unroll
    for (int reg = 0; reg < 4; ++reg) {
      const int row = r0 + 16 * mt + 4 * q + reg;
      const bool ok = row < nnodes;
      float ps = 0.f, pd = 0.f;
      #pragma unroll
      for (int nt = 0; nt < 4; ++nt) {
        const float v = acc[mt][nt][reg];
        if (ok) h[(size_t)row * 256 + 64 * wv + 16 * nt + l15] = f2bf(v);
        ps += v * atts[nt];
        pd += v * attd[nt];
      }
      #pragma unroll
      for (int off = 8; off; off >>= 1) {
        ps += __shfl_down(ps, off, 16);
        pd += __shfl_down(pd, off, 16);
      }
      if (ok && l15 == 0) {
        a_src[row * 4 + wv] = ps;
        a_dst[row * 4 + wv] = pd;
      }
    }
  }
}

// ---------------------------------------------------------------------------
// 3-phase hierarchical exclusive scan (unchanged)
// ---------------------------------------------------------------------------
__global__ __launch_bounds__(256) void scan_p1(const int* __restrict__ deg,
                                               int* __restrict__ bsum, int n)
{
  __shared__ int ws[4];
  const int t = threadIdx.x, lane = t & 63, wv = t >> 6;
  const int base = blockIdx.x * 1024 + t * 4;
  int4 v = make_int4(0, 0, 0, 0);
  if (base + 3 < n) v = *(const int4*)&deg[base];
  else {
    if (base + 0 < n) v.x = deg[base + 0];
    if (base + 1 < n) v.y = deg[base + 1];
    if (base + 2 < n) v.z = deg[base + 2];
  }
  int s = (v.x + v.y) + (v.z + v.w);
  #pragma unroll
  for (int off = 32; off; off >>= 1) s += __shfl_down(s, off, 64);
  if (lane == 0) ws[wv] = s;
  __syncthreads();
  if (t == 0) bsum[blockIdx.x] = (ws[0] + ws[1]) + (ws[2] + ws[3]);
}

__global__ __launch_bounds__(1024) void scan_p2(const int* __restrict__ bsum,
                                                int* __restrict__ boff,
                                                int* __restrict__ rowptr,
                                                int nb, int n)
{
  __shared__ int wsum[16], woff[16];
  const int t = threadIdx.x, lane = t & 63, wv = t >> 6;
  int v = (t < nb) ? bsum[t] : 0;
  int sc = v;
  #pragma unroll
  for (int off = 1; off < 64; off <<= 1) {
    int u = __shfl_up(sc, off, 64);
    if (lane >= off) sc += u;
  }
  if (lane == 63) wsum[wv] = sc;
  __syncthreads();
  if (t == 0) {
    int run = 0;
    #pragma unroll
    for (int i = 0; i < 16; ++i) { int x = wsum[i]; woff[i] = run; run += x; }
    rowptr[n] = run;
  }
  __syncthreads();
  if (t < nb) boff[t] = woff[wv] + sc - v;
}

__global__ __launch_bounds__(256) void scan_p3(const int* __restrict__ deg,
                                               const int* __restrict__ boff,
                                               int* __restrict__ rowptr,
                                               int* __restrict__ cursor, int n)
{
  __shared__ int wsum[4], woff[4];
  const int t = threadIdx.x, lane = t & 63, wv = t >> 6;
  const int base = blockIdx.x * 1024 + t * 4;
  int4 v = make_int4(0, 0, 0, 0);
  if (base + 3 < n) v = *(const int4*)&deg[base];
  else {
    if (base + 0 < n) v.x = deg[base + 0];
    if (base + 1 < n) v.y = deg[base + 1];
    if (base + 2 < n) v.z = deg[base + 2];
  }
  const int s = (v.x + v.y) + (v.z + v.w);
  int sc = s;
  #pragma unroll
  for (int off = 1; off < 64; off <<= 1) {
    int u = __shfl_up(sc, off, 64);
    if (lane >= off) sc += u;
  }
  if (lane == 63) wsum[wv] = sc;
  __syncthreads();
  if (t == 0) {
    int run = 0;
    #pragma unroll
    for (int i = 0; i < 4; ++i) { int x = wsum[i]; woff[i] = run; run += x; }
  }
  __syncthreads();
  int excl = boff[blockIdx.x] + woff[wv] + (sc - s);
  int4 r;
  r.x = excl;
  r.y = r.x + v.x;
  r.z = r.y + v.y;
  r.w = r.z + v.z;
  if (base + 3 < n) {
    *(int4*)&rowptr[base] = r;
    *(int4*)&cursor[base] = r;
  } else {
    if (base + 0 < n) { rowptr[base + 0] = r.x; cursor[base + 0] = r.x; }
    if (base + 1 < n) { rowptr[base + 1] = r.y; cursor[base + 1] = r.y; }
    if (base + 2 < n) { rowptr[base + 2] = r.z; cursor[base + 2] = r.z; }
  }
}

// ---------------------------------------------------------------------------
// fill_csr, XCD-grouped + int4 edge loads (unchanged from round 8)
// ---------------------------------------------------------------------------
__device__ __forceinline__ void fill_one(
    int s, int d, int dlo, int dhi, const float* __restrict__ a_src,
    const float* __restrict__ a_dst, int* __restrict__ cursor,
    int* __restrict__ csr_src, float4* __restrict__ wexp)
{
  if (d < dlo || d >= dhi) return;
  const int pos = atomicAdd(&cursor[d], 1);
  csr_src[pos] = s;
  const float4 as = ((const float4*)a_src)[s];
  const float4 ad = ((const float4*)a_dst)[d];
  float4 al;
  al.x = as.x + ad.x; al.y = as.y + ad.y;
  al.z = as.z + ad.z; al.w = as.w + ad.w;
  al.x = al.x > 0.f ? al.x : NEG_SLOPE * al.x;
  al.y = al.y > 0.f ? al.y : NEG_SLOPE * al.y;
  al.z = al.z > 0.f ? al.z : NEG_SLOPE * al.z;
  al.w = al.w > 0.f ? al.w : NEG_SLOPE * al.w;
  al.x = expf(al.x); al.y = expf(al.y); al.z = expf(al.z); al.w = expf(al.w);
  wexp[pos] = al;
}

__global__ __launch_bounds__(256) void fill_csr(
    const int* __restrict__ ei, const float* __restrict__ a_src,
    const float* __restrict__ a_dst, int* __restrict__ cursor,
    int* __restrict__ csr_src, float4* __restrict__ wexp, int E, int nnodes)
{
  const int g    = blockIdx.x & 7;
  const int bg   = blockIdx.x >> 3;
  const int nbg  = gridDim.x >> 3;
  const int gsz  = (nnodes + 7) >> 3;
  const int dlo  = g * gsz;
  const int dhi  = min(dlo + gsz, nnodes);
  const int E4   = E >> 2;

  for (int c = bg * 256 + threadIdx.x; c < E4; c += nbg * 256) {
    const int4 d4 = *(const int4*)&ei[E + 4 * c];
    const int4 s4 = *(const int4*)&ei[4 * c];
    fill_one(s4.x, d4.x, dlo, dhi, a_src, a_dst, cursor, csr_src, wexp);
    fill_one(s4.y, d4.y, dlo, dhi, a_src, a_dst, cursor, csr_src, wexp);
    fill_one(s4.z, d4.z, dlo, dhi, a_src, a_dst, cursor, csr_src, wexp);
    fill_one(s4.w, d4.w, dlo, dhi, a_src, a_dst, cursor, csr_src, wexp);
  }
  for (int e = E4 * 4 + bg * 256 + threadIdx.x; e < E; e += nbg * 256)
    fill_one(ei[e], ei[E + e], dlo, dhi, a_src, a_dst, cursor, csr_src, wexp);
}

// ---------------------------------------------------------------------------
// K3: gather with bijective XCD swizzle (grid multiple of 8). Unchanged.
// ---------------------------------------------------------------------------
__device__ __forceinline__ float4 ld_h(const unsigned short* __restrict__ h,
                                       int row, int cb)
{
  const ushort4 u = *(const ushort4*)&h[(size_t)row * 256 + cb];
  return make_float4(bf2f(u.x), bf2f(u.y), bf2f(u.z), bf2f(u.w));
}

__global__ __launch_bounds__(256) void gather_kernel(
    const int* __restrict__ rowptr, const int* __restrict__ csr_src,
    const float* __restrict__ wexp, const unsigned short* __restrict__ h,
    const float* __restrict__ a_src, const float* __restrict__ a_dst,
    const float* __restrict__ bias, float* __restrict__ out, int n)
{
  const int per8 = gridDim.x >> 3;   // gridDim.x is a multiple of 8
  const int vb   = (blockIdx.x & 7) * per8 + (blockIdx.x >> 3);
  const int wave = threadIdx.x >> 6;
  const int lane = threadIdx.x & 63;
  const int d = vb * 4 + wave;
  if (d >= n) return;

  const int head = lane >> 4;
  const int cb   = lane * 4;

  // self-loop (weight computed inline; not in csr)
  float alpha = a_src[d * 4 + head] + a_dst[d * 4 + head];
  alpha = alpha > 0.f ? alpha : NEG_SLOPE * alpha;
  float w = expf(alpha);
  float dsum = w;
  float4 hv = ld_h(h, d, cb);
  float4 acc = make_float4(w * hv.x, w * hv.y, w * hv.z, w * hv.w);

  int j = rowptr[d];
  const int end = rowptr[d + 1];

  for (; j + 7 < end; j += 8) {
    const int4 sa = *(const int4*)&csr_src[j];
    const int4 sb = *(const int4*)&csr_src[j + 4];
    float wj[8];
    #pragma unroll
    for (int k = 0; k < 8; ++k) wj[k] = wexp[(j + k) * 4 + head];
    const float4 h0 = ld_h(h, sa.x, cb);
    const float4 h1 = ld_h(h, sa.y, cb);
    const float4 h2 = ld_h(h, sa.z, cb);
    const float4 h3 = ld_h(h, sa.w, cb);
    const float4 h4 = ld_h(h, sb.x, cb);
    const float4 h5 = ld_h(h, sb.y, cb);
    const float4 h6 = ld_h(h, sb.z, cb);
    const float4 h7 = ld_h(h, sb.w, cb);
    dsum += ((wj[0] + wj[1]) + (wj[2] + wj[3])) + ((wj[4] + wj[5]) + (wj[6] + wj[7]));
    acc.x += wj[0] * h0.x + wj[1] * h1.x + wj[2] * h2.x + wj[3] * h3.x
           + wj[4] * h4.x + wj[5] * h5.x + wj[6] * h6.x + wj[7] * h7.x;
    acc.y += wj[0] * h0.y + wj[1] * h1.y + wj[2] * h2.y + wj[3] * h3.y
           + wj[4] * h4.y + wj[5] * h5.y + wj[6] * h6.y + wj[7] * h7.y;
    acc.z += wj[0] * h0.z + wj[1] * h1.z + wj[2] * h2.z + wj[3] * h3.z
           + wj[4] * h4.z + wj[5] * h5.z + wj[6] * h6.z + wj[7] * h7.z;
    acc.w += wj[0] * h0.w + wj[1] * h1.w + wj[2] * h2.w + wj[3] * h3.w
           + wj[4] * h4.w + wj[5] * h5.w + wj[6] * h6.w + wj[7] * h7.w;
  }
  for (; j < end; ++j) {
    const int s0 = csr_src[j];
    const float w0 = wexp[j * 4 + head];
    const float4 h0 = ld_h(h, s0, cb);
    dsum += w0;
    acc.x += w0 * h0.x; acc.y += w0 * h0.y;
    acc.z += w0 * h0.z; acc.w += w0 * h0.w;
  }

  const float inv = 1.f / (dsum + 1e-16f);
  const float4 b4 = ((const float4*)bias)[lane];
  float4 o;
  o.x = acc.x * inv + b4.x; o.x = o.x > 0.f ? o.x : 0.f;
  o.y = acc.y * inv + b4.y; o.y = o.y > 0.f ? o.y : 0.f;
  o.z = acc.z * inv + b4.z; o.z = o.z > 0.f ? o.z : 0.f;
  o.w = acc.w * inv + b4.w; o.w = o.w > 0.f ? o.w : 0.f;
  *(float4*)&out[(size_t)d * 256 + cb] = o;
}

extern "C" void kernel_launch(void* const* d_in, const int* in_sizes, int n_in,
                              void* d_out, int out_size, void* d_ws, size_t ws_size,
                              hipStream_t stream)
{
  const float* x       = (const float*)d_in[0];
  const int*   ei      = (const int*)d_in[1];
  const float* W       = (const float*)d_in[2];
  const float* att_src = (const float*)d_in[3];
  const float* att_dst = (const float*)d_in[4];
  const float* bias    = (const float*)d_in[5];

  const int nnodes = in_sizes[0] / HC;   // 50000
  const int E      = in_sizes[1] / 2;    // 800000
  const int nb     = (nnodes + 1023) / 1024;      // scan blocks (49)
  const int degBlocks    = (E + 1023) / 1024;     // 782
  const int gemmBlocks   = (nnodes + 63) / 64;    // 782
  const int gatherBlocks = (((nnodes + 3) / 4) + 7) & ~7;  // multiple of 8

  float* out = (float*)d_out;
  char* ws = (char*)d_ws;
  // Workspace (~44 MB), all segments 16B-aligned:
  unsigned short* h  = (unsigned short*)ws;                          // nnodes*256 bf16
  float* a_src = (float*)(ws + (size_t)nnodes * HC * 2);             // nnodes*4 f32
  float* a_dst = a_src + (size_t)nnodes * 4;
  unsigned short* Wt = (unsigned short*)(a_dst + (size_t)nnodes * 4); // 256*256 bf16
  int* deg    = (int*)((char*)Wt + 256 * 256 * 2);                   // nnodes
  int* rowptr = deg + nnodes;                                        // nnodes+1 (pad x4)
  int* cursor = rowptr + ((nnodes + 1 + 3) & ~3);                    // nnodes
  int* bsum   = cursor + nnodes;                                     // nb
  int* boff   = bsum + ((nb + 3) & ~3);                              // nb
  float4* wexp = (float4*)(boff + ((nb + 3) & ~3));                  // E float4 (12.8 MB)
  int* csr    = (int*)(wexp + E);                                    // E

  hipMemsetAsync(deg, 0, (size_t)nnodes * sizeof(int), stream);

  wt_deg<<<256 + degBlocks, 256, 0, stream>>>(W, Wt, ei, deg, E);

  gemm_mfma<<<gemmBlocks, 256, 0, stream>>>(
      x, Wt, att_src, att_dst, h, a_src, a_dst, nnodes);

  scan_p1<<<nb, 256, 0, stream>>>(deg, bsum, nnodes);
  scan_p2<<<1, 1024, 0, stream>>>(bsum, boff, rowptr, nb, nnodes);
  scan_p3<<<nb, 256, 0, stream>>>(deg, boff, rowptr, cursor, nnodes);

  fill_csr<<<1024, 256, 0, stream>>>(ei, a_src, a_dst, cursor, csr,
                                     (float4*)wexp, E, nnodes);

  gather_kernel<<<gatherBlocks, 256, 0, stream>>>(
      rowptr, csr, (const float*)wexp, h, a_src, a_dst, bias, out, nnodes);
}

// Round 10
// 279.571 us; speedup vs baseline: 1.0536x; 1.0112x over previous
//
#include <hip/hip_runtime.h>
#include <hip/hip_bf16.h>

#define HC 256        // HEADS*OUT_CH
#define NEG_SLOPE 0.2f
#define LDA 264       // padded LDS A-row stride in bf16 elems (528 B, 16B-aligned)

typedef short short8_t __attribute__((ext_vector_type(8)));
typedef float float4_t __attribute__((ext_vector_type(4)));

__device__ __forceinline__ unsigned short f2bf(float f) {
  unsigned u = __float_as_uint(f);
  return (unsigned short)((u + 0x7fffu + ((u >> 16) & 1u)) >> 16);  // RNE
}
__device__ __forceinline__ float bf2f(unsigned short b) {
  return __uint_as_float(((unsigned)b) << 16);
}
__device__ __forceinline__ unsigned pk2bf(float a, float b) {
  __hip_bfloat162 b2 = __float22bfloat162_rn(make_float2(a, b));
  return *(unsigned*)&b2;
}

// ---------------------------------------------------------------------------
// K0: fused Wt-transpose + degree histogram.
// ---------------------------------------------------------------------------
__global__ void wt_deg(const float* __restrict__ W, unsigned short* __restrict__ Wt,
                       const int* __restrict__ ei, int* __restrict__ deg, int E)
{
  if (blockIdx.x < 256) {
    const int k = blockIdx.x;
    const int n = threadIdx.x;
    Wt[n * 256 + k] = f2bf(W[k * 256 + n]);
    return;
  }
  const int base = ((blockIdx.x - 256) * 256 + threadIdx.x) * 4;
  if (base + 3 < E) {
    const int4 d4 = *(const int4*)&ei[E + base];
    atomicAdd(&deg[d4.x], 1);
    atomicAdd(&deg[d4.y], 1);
    atomicAdd(&deg[d4.z], 1);
    atomicAdd(&deg[d4.w], 1);
  } else {
    for (int e = base; e < E; ++e) atomicAdd(&deg[ei[E + e]], 1);
  }
}

// ---------------------------------------------------------------------------
// K1: h = x @ W via bf16 MFMA, SWAPPED operands: mfma(Wt-frag, x-frag) gives
// D[channel][x-row] — each lane holds 4 CONSECUTIVE channels per tile, so the
// h-write is 16 uint2 stores (2x cvt_pk each) instead of 128 scalar ushort
// stores, and a_src/a_dst reduce with 2 shfl_xor instead of 4 shfl_down.
// A staged in LDS once (single barrier), B straight from L2-resident Wt.
// ---------------------------------------------------------------------------
__global__ __launch_bounds__(256) void gemm_mfma(
    const float* __restrict__ x, const unsigned short* __restrict__ Wt,
    const float* __restrict__ att_src, const float* __restrict__ att_dst,
    unsigned short* __restrict__ h, float* __restrict__ a_src,
    float* __restrict__ a_dst, int nnodes)
{
  __shared__ unsigned short As[64 * LDA];   // 33792 B
  const int t    = threadIdx.x;
  const int wv   = t >> 6;
  const int lane = t & 63;
  const int r0   = blockIdx.x * 64;

  // stage A: thread t -> row t>>2, k-chunk (t&3)*64
  {
    const int row = t >> 2;
    const int kc  = (t & 3) * 64;
    const int gr  = r0 + row;
    unsigned pk[32];
    if (gr < nnodes) {
      const float4* p = (const float4*)(x + (size_t)gr * 256 + kc);
      #pragma unroll
      for (int i = 0; i < 16; ++i) {
        const float4 v = p[i];
        pk[2 * i]     = pk2bf(v.x, v.y);
        pk[2 * i + 1] = pk2bf(v.z, v.w);
      }
    } else {
      #pragma unroll
      for (int i = 0; i < 32; ++i) pk[i] = 0;
    }
    uint4* d = (uint4*)&As[row * LDA + kc];
    #pragma unroll
    for (int i = 0; i < 8; ++i)
      d[i] = make_uint4(pk[4 * i], pk[4 * i + 1], pk[4 * i + 2], pk[4 * i + 3]);
  }
  __syncthreads();

  const int q = lane >> 4, l15 = lane & 15;
  float4_t acc[4][4] = {};   // [mt][nt]: D[c=16nt+4q+reg][r=16mt+l15]

  #pragma unroll
  for (int ks = 0; ks < 8; ++ks) {
    const int ko = ks * 32 + q * 8;
    short8_t bfr[4], af[4];
    #pragma unroll
    for (int nt = 0; nt < 4; ++nt)
      bfr[nt] = *(const short8_t*)&Wt[(size_t)(64 * wv + 16 * nt + l15) * 256 + ko];
    #pragma unroll
    for (int mt = 0; mt < 4; ++mt)
      af[mt] = *(const short8_t*)&As[(16 * mt + l15) * LDA + ko];
    #pragma unroll
    for (int mt = 0; mt < 4; ++mt)
      #pragma unroll
      for (int nt = 0; nt < 4; ++nt)
        acc[mt][nt] = __builtin_amdgcn_mfma_f32_16x16x32_bf16(
            bfr[nt], af[mt], acc[mt][nt], 0, 0, 0);
  }

  // epilogue: lane (q,l15) holds channels 64wv+16nt+4q+{0..3} of row 16mt+l15
  float4 atts[4], attd[4];
  #pragma unroll
  for (int nt = 0; nt < 4; ++nt) {
    atts[nt] = ((const float4*)att_src)[16 * wv + 4 * nt + q];
    attd[nt] = ((const float4*)att_dst)[16 * wv + 4 * nt + q];
  }

  #pragma unroll
  for (int mt = 0; mt < 4; ++mt) {
    const int row = r0 + 16 * mt + l15;
    const bool ok = row < nnodes;
    float ps = 0.f, pd = 0.f;
    #pragma unroll
    for (int nt = 0; nt < 4; ++nt) {
      const float4_t a = acc[mt][nt];
      if (ok) {
        uint2 u = make_uint2(pk2bf(a[0], a[1]), pk2bf(a[2], a[3]));
        *(uint2*)&h[(size_t)row * 256 + 64 * wv + 16 * nt + 4 * q] = u;
      }
      ps += a[0] * atts[nt].x + a[1] * atts[nt].y + a[2] * atts[nt].z + a[3] * atts[nt].w;
      pd += a[0] * attd[nt].x + a[1] * attd[nt].y + a[2] * attd[nt].z + a[3] * attd[nt].w;
    }
    ps += __shfl_xor(ps, 16, 64); ps += __shfl_xor(ps, 32, 64);
    pd += __shfl_xor(pd, 16, 64); pd += __shfl_xor(pd, 32, 64);
    if (ok && q == 0) {
      a_src[row * 4 + wv] = ps;
      a_dst[row * 4 + wv] = pd;
    }
  }
}

// ---------------------------------------------------------------------------
// 3-phase hierarchical exclusive scan (unchanged)
// ---------------------------------------------------------------------------
__global__ __launch_bounds__(256) void scan_p1(const int* __restrict__ deg,
                                               int* __restrict__ bsum, int n)
{
  __shared__ int ws[4];
  const int t = threadIdx.x, lane = t & 63, wv = t >> 6;
  const int base = blockIdx.x * 1024 + t * 4;
  int4 v = make_int4(0, 0, 0, 0);
  if (base + 3 < n) v = *(const int4*)&deg[base];
  else {
    if (base + 0 < n) v.x = deg[base + 0];
    if (base + 1 < n) v.y = deg[base + 1];
    if (base + 2 < n) v.z = deg[base + 2];
  }
  int s = (v.x + v.y) + (v.z + v.w);
  #pragma unroll
  for (int off = 32; off; off >>= 1) s += __shfl_down(s, off, 64);
  if (lane == 0) ws[wv] = s;
  __syncthreads();
  if (t == 0) bsum[blockIdx.x] = (ws[0] + ws[1]) + (ws[2] + ws[3]);
}

__global__ __launch_bounds__(1024) void scan_p2(const int* __restrict__ bsum,
                                                int* __restrict__ boff,
                                                int* __restrict__ rowptr,
                                                int nb, int n)
{
  __shared__ int wsum[16], woff[16];
  const int t = threadIdx.x, lane = t & 63, wv = t >> 6;
  int v = (t < nb) ? bsum[t] : 0;
  int sc = v;
  #pragma unroll
  for (int off = 1; off < 64; off <<= 1) {
    int u = __shfl_up(sc, off, 64);
    if (lane >= off) sc += u;
  }
  if (lane == 63) wsum[wv] = sc;
  __syncthreads();
  if (t == 0) {
    int run = 0;
    #pragma unroll
    for (int i = 0; i < 16; ++i) { int x = wsum[i]; woff[i] = run; run += x; }
    rowptr[n] = run;
  }
  __syncthreads();
  if (t < nb) boff[t] = woff[wv] + sc - v;
}

__global__ __launch_bounds__(256) void scan_p3(const int* __restrict__ deg,
                                               const int* __restrict__ boff,
                                               int* __restrict__ rowptr,
                                               int* __restrict__ cursor, int n)
{
  __shared__ int wsum[4], woff[4];
  const int t = threadIdx.x, lane = t & 63, wv = t >> 6;
  const int base = blockIdx.x * 1024 + t * 4;
  int4 v = make_int4(0, 0, 0, 0);
  if (base + 3 < n) v = *(const int4*)&deg[base];
  else {
    if (base + 0 < n) v.x = deg[base + 0];
    if (base + 1 < n) v.y = deg[base + 1];
    if (base + 2 < n) v.z = deg[base + 2];
  }
  const int s = (v.x + v.y) + (v.z + v.w);
  int sc = s;
  #pragma unroll
  for (int off = 1; off < 64; off <<= 1) {
    int u = __shfl_up(sc, off, 64);
    if (lane >= off) sc += u;
  }
  if (lane == 63) wsum[wv] = sc;
  __syncthreads();
  if (t == 0) {
    int run = 0;
    #pragma unroll
    for (int i = 0; i < 4; ++i) { int x = wsum[i]; woff[i] = run; run += x; }
  }
  __syncthreads();
  int excl = boff[blockIdx.x] + woff[wv] + (sc - s);
  int4 r;
  r.x = excl;
  r.y = r.x + v.x;
  r.z = r.y + v.y;
  r.w = r.z + v.z;
  if (base + 3 < n) {
    *(int4*)&rowptr[base] = r;
    *(int4*)&cursor[base] = r;
  } else {
    if (base + 0 < n) { rowptr[base + 0] = r.x; cursor[base + 0] = r.x; }
    if (base + 1 < n) { rowptr[base + 1] = r.y; cursor[base + 1] = r.y; }
    if (base + 2 < n) { rowptr[base + 2] = r.z; cursor[base + 2] = r.z; }
  }
}

// ---------------------------------------------------------------------------
// fill_csr, XCD-grouped. Emits unified 16-B edge records:
//   rec = { src:i32, w01:2xbf16, w23:2xbf16, pad }.
// src loaded lazily (only for in-range edges). One uint4 store per edge.
// ---------------------------------------------------------------------------
__device__ __forceinline__ void fill_one(
    const int* __restrict__ ei, int e, int d, int dlo, int dhi,
    const float* __restrict__ a_src, const float* __restrict__ a_dst,
    int* __restrict__ cursor, uint4* __restrict__ rec)
{
  if (d < dlo || d >= dhi) return;
  const int s = ei[e];
  const int pos = atomicAdd(&cursor[d], 1);
  const float4 as = ((const float4*)a_src)[s];
  const float4 ad = ((const float4*)a_dst)[d];
  float4 al;
  al.x = as.x + ad.x; al.y = as.y + ad.y;
  al.z = as.z + ad.z; al.w = as.w + ad.w;
  al.x = al.x > 0.f ? al.x : NEG_SLOPE * al.x;
  al.y = al.y > 0.f ? al.y : NEG_SLOPE * al.y;
  al.z = al.z > 0.f ? al.z : NEG_SLOPE * al.z;
  al.w = al.w > 0.f ? al.w : NEG_SLOPE * al.w;
  al.x = expf(al.x); al.y = expf(al.y); al.z = expf(al.z); al.w = expf(al.w);
  rec[pos] = make_uint4((unsigned)s, pk2bf(al.x, al.y), pk2bf(al.z, al.w), 0u);
}

__global__ __launch_bounds__(256) void fill_csr(
    const int* __restrict__ ei, const float* __restrict__ a_src,
    const float* __restrict__ a_dst, int* __restrict__ cursor,
    uint4* __restrict__ rec, int E, int nnodes)
{
  const int g    = blockIdx.x & 7;
  const int bg   = blockIdx.x >> 3;
  const int nbg  = gridDim.x >> 3;
  const int gsz  = (nnodes + 7) >> 3;
  const int dlo  = g * gsz;
  const int dhi  = min(dlo + gsz, nnodes);
  const int E4   = E >> 2;

  for (int c = bg * 256 + threadIdx.x; c < E4; c += nbg * 256) {
    const int4 d4 = *(const int4*)&ei[E + 4 * c];
    fill_one(ei, 4 * c + 0, d4.x, dlo, dhi, a_src, a_dst, cursor, rec);
    fill_one(ei, 4 * c + 1, d4.y, dlo, dhi, a_src, a_dst, cursor, rec);
    fill_one(ei, 4 * c + 2, d4.z, dlo, dhi, a_src, a_dst, cursor, rec);
    fill_one(ei, 4 * c + 3, d4.w, dlo, dhi, a_src, a_dst, cursor, rec);
  }
  for (int e = E4 * 4 + bg * 256 + threadIdx.x; e < E; e += nbg * 256)
    fill_one(ei, e, ei[E + e], dlo, dhi, a_src, a_dst, cursor, rec);
}

// ---------------------------------------------------------------------------
// K3: gather over unified records. One uint4 load per edge (src + 4 bf16
// weights), one 8-B h load per lane. Unroll 8 + 4 + scalar tail.
// ---------------------------------------------------------------------------
__device__ __forceinline__ float4 ld_h(const unsigned short* __restrict__ h,
                                       int row, int cb)
{
  const ushort4 u = *(const ushort4*)&h[(size_t)row * 256 + cb];
  return make_float4(bf2f(u.x), bf2f(u.y), bf2f(u.z), bf2f(u.w));
}
__device__ __forceinline__ float wsel(uint4 r, int head)
{
  const unsigned pw = (head & 2) ? r.z : r.y;
  const unsigned us = (head & 1) ? (pw >> 16) : (pw & 0xffffu);
  return __uint_as_float(us << 16);
}

__global__ __launch_bounds__(256) void gather_kernel(
    const int* __restrict__ rowptr, const uint4* __restrict__ rec,
    const unsigned short* __restrict__ h, const float* __restrict__ a_src,
    const float* __restrict__ a_dst, const float* __restrict__ bias,
    float* __restrict__ out, int n)
{
  const int per8 = gridDim.x >> 3;   // gridDim.x is a multiple of 8
  const int vb   = (blockIdx.x & 7) * per8 + (blockIdx.x >> 3);
  const int wave = threadIdx.x >> 6;
  const int lane = threadIdx.x & 63;
  const int d = vb * 4 + wave;
  if (d >= n) return;

  const int head = lane >> 4;
  const int cb   = lane * 4;

  // self-loop (weight computed inline; not in the record stream)
  float alpha = a_src[d * 4 + head] + a_dst[d * 4 + head];
  alpha = alpha > 0.f ? alpha : NEG_SLOPE * alpha;
  float w = expf(alpha);
  float dsum = w;
  float4 hv = ld_h(h, d, cb);
  float4 acc = make_float4(w * hv.x, w * hv.y, w * hv.z, w * hv.w);

  int j = rowptr[d];
  const int end = rowptr[d + 1];

  for (; j + 7 < end; j += 8) {
    uint4 r[8];
    #pragma unroll
    for (int k = 0; k < 8; ++k) r[k] = rec[j + k];
    float4 hx[8];
    #pragma unroll
    for (int k = 0; k < 8; ++k) hx[k] = ld_h(h, (int)r[k].x, cb);
    float wj[8];
    #pragma unroll
    for (int k = 0; k < 8; ++k) wj[k] = wsel(r[k], head);
    dsum += ((wj[0] + wj[1]) + (wj[2] + wj[3])) + ((wj[4] + wj[5]) + (wj[6] + wj[7]));
    #pragma unroll
    for (int k = 0; k < 8; ++k) {
      acc.x += wj[k] * hx[k].x;
      acc.y += wj[k] * hx[k].y;
      acc.z += wj[k] * hx[k].z;
      acc.w += wj[k] * hx[k].w;
    }
  }
  for (; j + 3 < end; j += 4) {
    uint4 r[4];
    #pragma unroll
    for (int k = 0; k < 4; ++k) r[k] = rec[j + k];
    float4 hx[4];
    #pragma unroll
    for (int k = 0; k < 4; ++k) hx[k] = ld_h(h, (int)r[k].x, cb);
    #pragma unroll
    for (int k = 0; k < 4; ++k) {
      const float wk = wsel(r[k], head);
      dsum += wk;
      acc.x += wk * hx[k].x;
      acc.y += wk * hx[k].y;
      acc.z += wk * hx[k].z;
      acc.w += wk * hx[k].w;
    }
  }
  for (; j < end; ++j) {
    const uint4 r0 = rec[j];
    const float4 h0 = ld_h(h, (int)r0.x, cb);
    const float w0 = wsel(r0, head);
    dsum += w0;
    acc.x += w0 * h0.x; acc.y += w0 * h0.y;
    acc.z += w0 * h0.z; acc.w += w0 * h0.w;
  }

  const float inv = 1.f / (dsum + 1e-16f);
  const float4 b4 = ((const float4*)bias)[lane];
  float4 o;
  o.x = acc.x * inv + b4.x; o.x = o.x > 0.f ? o.x : 0.f;
  o.y = acc.y * inv + b4.y; o.y = o.y > 0.f ? o.y : 0.f;
  o.z = acc.z * inv + b4.z; o.z = o.z > 0.f ? o.z : 0.f;
  o.w = acc.w * inv + b4.w; o.w = o.w > 0.f ? o.w : 0.f;
  *(float4*)&out[(size_t)d * 256 + cb] = o;
}

extern "C" void kernel_launch(void* const* d_in, const int* in_sizes, int n_in,
                              void* d_out, int out_size, void* d_ws, size_t ws_size,
                              hipStream_t stream)
{
  const float* x       = (const float*)d_in[0];
  const int*   ei      = (const int*)d_in[1];
  const float* W       = (const float*)d_in[2];
  const float* att_src = (const float*)d_in[3];
  const float* att_dst = (const float*)d_in[4];
  const float* bias    = (const float*)d_in[5];

  const int nnodes = in_sizes[0] / HC;   // 50000
  const int E      = in_sizes[1] / 2;    // 800000
  const int nb     = (nnodes + 1023) / 1024;      // scan blocks (49)
  const int degBlocks    = (E + 1023) / 1024;     // 782
  const int gemmBlocks   = (nnodes + 63) / 64;    // 782
  const int gatherBlocks = (((nnodes + 3) / 4) + 7) & ~7;  // multiple of 8

  float* out = (float*)d_out;
  char* ws = (char*)d_ws;
  // Workspace (~41 MB), all segments 16B-aligned:
  unsigned short* h  = (unsigned short*)ws;                          // nnodes*256 bf16
  float* a_src = (float*)(ws + (size_t)nnodes * HC * 2);             // nnodes*4 f32
  float* a_dst = a_src + (size_t)nnodes * 4;
  unsigned short* Wt = (unsigned short*)(a_dst + (size_t)nnodes * 4); // 256*256 bf16
  int* deg    = (int*)((char*)Wt + 256 * 256 * 2);                   // nnodes
  int* rowptr = deg + nnodes;                                        // nnodes+1 (pad x4)
  int* cursor = rowptr + ((nnodes + 1 + 3) & ~3);                    // nnodes
  int* bsum   = cursor + nnodes;                                     // nb
  int* boff   = bsum + ((nb + 3) & ~3);                              // nb
  uint4* rec  = (uint4*)(boff + ((nb + 3) & ~3));                    // E x 16 B

  hipMemsetAsync(deg, 0, (size_t)nnodes * sizeof(int), stream);

  wt_deg<<<256 + degBlocks, 256, 0, stream>>>(W, Wt, ei, deg, E);

  gemm_mfma<<<gemmBlocks, 256, 0, stream>>>(
      x, Wt, att_src, att_dst, h, a_src, a_dst, nnodes);

  scan_p1<<<nb, 256, 0, stream>>>(deg, bsum, nnodes);
  scan_p2<<<1, 1024, 0, stream>>>(bsum, boff, rowptr, nb, nnodes);
  scan_p3<<<nb, 256, 0, stream>>>(deg, boff, rowptr, cursor, nnodes);

  fill_csr<<<1024, 256, 0, stream>>>(ei, a_src, a_dst, cursor, rec, E, nnodes);

  gather_kernel<<<gatherBlocks, 256, 0, stream>>>(
      rowptr, rec, h, a_src, a_dst, bias, out, nnodes);
}